// Round 8
// baseline (9447.676 us; speedup 1.0000x reference)
//
#include <hip/hip_runtime.h>
#include <math.h>

// Round 8: occupancy attack. 2 blocks/CU (LDS 124KB -> 74.5KB) via:
//  - q kept in producer-wave registers; kq consumes it through a rotating
//    8-step double-buffer (qbuf) in strict i-ascending order (bit-exact).
//  - kT and sm chunked by s (32/33 rows); kq/softmax/att/pre1 per chunk;
//    kc chunk buffer doubles as att chunk buffer. pre1 acc chains unchanged.
//  - stage-2 v2 in registers; att2 via wave butterfly (post-final-softmax,
//    reassociation-safe like pre2/L3).
// All chains feeding any softmax stay bit-identical to rounds 5-7.

#define YQ(s, q) ((s) * 128 + 4 * ((q) ^ ((s) & 7)))
#define QS 20            // qbuf row stride (floats)
#define QBUF 1304        // floats per qbuf half (64*20 + pad)

__global__
__attribute__((amdgpu_flat_work_group_size(1024, 1024)))
void literal_kernel(const float* __restrict__ in0,
                    const float* __restrict__ emb,
                    const float* __restrict__ wk11, const float* __restrict__ wq11,
                    const float* __restrict__ wv11,
                    const float* __restrict__ wk12, const float* __restrict__ wq12,
                    const float* __restrict__ wv12,
                    const float* __restrict__ l1,
                    const float* __restrict__ wk21, const float* __restrict__ wq21,
                    const float* __restrict__ wv21,
                    const float* __restrict__ wk22, const float* __restrict__ wq22,
                    const float* __restrict__ wv22,
                    const float* __restrict__ l2,
                    const float* __restrict__ L3, const float* __restrict__ L4,
                    float* __restrict__ out)
{
    __shared__ __align__(16) float vsh[128 * 68];   // v[i][t] s68; later y2 (YQ)
    __shared__ __align__(16) float kcsh[33 * 132];  // kT chunk [srel][i]; att chunk [srel*128+i]
    __shared__ __align__(16) float smc[33 * 68];    // sm chunk; later psum/l3p scratch
    __shared__ __align__(16) float qbufsh[2 * QBUF];
    __shared__ __align__(16) float q64sh[128];      // q[.][64] (st1) / q2[.][64] (st2)
    __shared__ float kq64sh[65];
    __shared__ __align__(16) float k2col[128];
    __shared__ __align__(16) float attr[128];
    __shared__ float lshf[66];
    __shared__ __align__(16) float smr[68];
    __shared__ float y4sh[128];

    const int tid  = threadIdx.x;
    const int lane = tid & 63;
    const int wu   = __builtin_amdgcn_readfirstlane(tid >> 6);   // wave 0..15
    const long b   = blockIdx.x;

    const float xr = in0[b * 64 + lane];   // x[lane]; x[64]=1 via col-64 path

    const int h4 = (tid & 31) * 4;
    const int sb = tid >> 5;               // 0..31
    float4 acc1[3];
    acc1[0] = make_float4(0.f, 0.f, 0.f, 0.f);
    acc1[1] = make_float4(0.f, 0.f, 0.f, 0.f);
    acc1[2] = make_float4(0.f, 0.f, 0.f, 0.f);

    const int i0 = wu * 8;

    // =================== stage 1 ===================
    for (int a = 0; a < 2; ++a) {
        const float* wk = a ? wk12 : wk11;
        const float* wq = a ? wq12 : wq11;
        const float* wv = a ? wv12 : wv11;

        // ---- projections (emb from global, r7 pattern). q,k stay in regs ----
        float aK[8], aQ[8], aV[8];
        #pragma unroll
        for (int r = 0; r < 8; ++r) { aK[r] = aQ[r] = aV[r] = 0.f; }
        float acc64 = 0.f;                       // lane<8:K64, 8..15:Q64, 16..23:V64
        {
            const int ch = lane >> 3;
            const float* Wc = (ch == 0) ? wk : ((ch == 1) ? wq : wv);
            const float* wcrow = Wc + (i0 + (lane & 7)) * 128;

            for (int jb = 0; jb < 16; ++jb) {
                const float* erow = emb + (jb * 8) * 65;
                float yv[8], y64v[8];
                #pragma unroll
                for (int u = 0; u < 8; ++u) {
                    yv[u]   = erow[u * 65 + lane] * xr;
                    y64v[u] = erow[u * 65 + 64];
                }
                #pragma unroll
                for (int r = 0; r < 8; ++r) {
                    const float* wkr = wk + (i0 + r) * 128 + jb * 8;
                    const float* wqr = wq + (i0 + r) * 128 + jb * 8;
                    const float* wvr = wv + (i0 + r) * 128 + jb * 8;
                    #pragma unroll
                    for (int u = 0; u < 8; ++u) {
                        aK[r] = fmaf(wkr[u], yv[u], aK[r]);
                        aQ[r] = fmaf(wqr[u], yv[u], aQ[r]);
                        aV[r] = fmaf(wvr[u], yv[u], aV[r]);
                    }
                }
                if (lane < 24) {
                    float4 c0 = *(const float4*)&wcrow[jb * 8];
                    float4 c1 = *(const float4*)&wcrow[jb * 8 + 4];
                    acc64 = fmaf(c0.x, y64v[0], acc64);
                    acc64 = fmaf(c0.y, y64v[1], acc64);
                    acc64 = fmaf(c0.z, y64v[2], acc64);
                    acc64 = fmaf(c0.w, y64v[3], acc64);
                    acc64 = fmaf(c1.x, y64v[4], acc64);
                    acc64 = fmaf(c1.y, y64v[5], acc64);
                    acc64 = fmaf(c1.z, y64v[6], acc64);
                    acc64 = fmaf(c1.w, y64v[7], acc64);
                }
            }
            #pragma unroll
            for (int r = 0; r < 8; ++r) vsh[(i0 + r) * 68 + lane] = aV[r];
            if (lane >= 16 && lane < 24) vsh[(i0 + (lane & 7)) * 68 + 64] = acc64;
            if (lane >= 8 && lane < 16)  q64sh[i0 + (lane & 7)] = acc64;
        }
        __syncthreads();   // v, q64 ready

        // ---- per-s-chunk: kq -> softmax -> att -> pre1 ----
        for (int cnk = 0; cnk < 2; ++cnk) {
            const int base = cnk * 32;
            const int nrows = cnk ? 33 : 32;

            // kc fill (from aK registers)
            if (cnk == 0) {
                if (lane < 32) {
                    *(float4*)&kcsh[lane * 132 + i0]     = make_float4(aK[0], aK[1], aK[2], aK[3]);
                    *(float4*)&kcsh[lane * 132 + i0 + 4] = make_float4(aK[4], aK[5], aK[6], aK[7]);
                }
            } else {
                if (lane >= 32) {
                    int srel = lane - 32;
                    *(float4*)&kcsh[srel * 132 + i0]     = make_float4(aK[0], aK[1], aK[2], aK[3]);
                    *(float4*)&kcsh[srel * 132 + i0 + 4] = make_float4(aK[4], aK[5], aK[6], aK[7]);
                }
                if (lane < 8) kcsh[32 * 132 + i0 + lane] = acc64;   // k col-64 -> row s=64
            }
            __syncthreads();

            // kq64[s] = sum_i k[i][s]*q[i][64]  (i-ascending, exact)
            if (tid < nrows) {
                const float* kr = &kcsh[tid * 132];
                float acc = 0.f;
                for (int i0b = 0; i0b < 128; i0b += 4) {
                    float4 kk = *(const float4*)&kr[i0b];
                    float4 qq = *(const float4*)&q64sh[i0b];
                    acc = fmaf(kk.x, qq.x, acc);
                    acc = fmaf(kk.y, qq.y, acc);
                    acc = fmaf(kk.z, qq.z, acc);
                    acc = fmaf(kk.w, qq.w, acc);
                }
                kq64sh[base + tid] = acc;
            }
            // qbuf prologue: step 0 (i=0..15) written by waves 0,1
            if (wu < 2) {
                *(float4*)&qbufsh[lane * QS + wu * 8]     = make_float4(aQ[0], aQ[1], aQ[2], aQ[3]);
                *(float4*)&qbufsh[lane * QS + wu * 8 + 4] = make_float4(aQ[4], aQ[5], aQ[6], aQ[7]);
            }
            __syncthreads();

            // kq c-loop: 8 steps of 16 i each, strict i-ascending
            float kqa0 = 0.f, kqa1 = 0.f, kqa2 = 0.f;
            const int s0rel = 2 * wu, s1rel = 2 * wu + 1;
            for (int c = 0; c < 8; ++c) {
                if (c < 7 && (wu >> 1) == c + 1) {     // waves 2c+2, 2c+3 write step c+1
                    int sel = (c + 1) & 1, off = (wu & 1) * 8;
                    *(float4*)&qbufsh[sel * QBUF + lane * QS + off]     = make_float4(aQ[0], aQ[1], aQ[2], aQ[3]);
                    *(float4*)&qbufsh[sel * QBUF + lane * QS + off + 4] = make_float4(aQ[4], aQ[5], aQ[6], aQ[7]);
                }
                const float* qr = &qbufsh[(c & 1) * QBUF + lane * QS];
                float4 q0 = *(const float4*)&qr[0];
                float4 q1 = *(const float4*)&qr[4];
                float4 q2v = *(const float4*)&qr[8];
                float4 q3 = *(const float4*)&qr[12];
                const int ib = 16 * c;
                {
                    const float* kr = &kcsh[s0rel * 132 + ib];
                    float4 k0 = *(const float4*)&kr[0], k1 = *(const float4*)&kr[4];
                    float4 k2 = *(const float4*)&kr[8], k3 = *(const float4*)&kr[12];
                    kqa0 = fmaf(k0.x, q0.x, kqa0); kqa0 = fmaf(k0.y, q0.y, kqa0);
                    kqa0 = fmaf(k0.z, q0.z, kqa0); kqa0 = fmaf(k0.w, q0.w, kqa0);
                    kqa0 = fmaf(k1.x, q1.x, kqa0); kqa0 = fmaf(k1.y, q1.y, kqa0);
                    kqa0 = fmaf(k1.z, q1.z, kqa0); kqa0 = fmaf(k1.w, q1.w, kqa0);
                    kqa0 = fmaf(k2.x, q2v.x, kqa0); kqa0 = fmaf(k2.y, q2v.y, kqa0);
                    kqa0 = fmaf(k2.z, q2v.z, kqa0); kqa0 = fmaf(k2.w, q2v.w, kqa0);
                    kqa0 = fmaf(k3.x, q3.x, kqa0); kqa0 = fmaf(k3.y, q3.y, kqa0);
                    kqa0 = fmaf(k3.z, q3.z, kqa0); kqa0 = fmaf(k3.w, q3.w, kqa0);
                }
                {
                    const float* kr = &kcsh[s1rel * 132 + ib];
                    float4 k0 = *(const float4*)&kr[0], k1 = *(const float4*)&kr[4];
                    float4 k2 = *(const float4*)&kr[8], k3 = *(const float4*)&kr[12];
                    kqa1 = fmaf(k0.x, q0.x, kqa1); kqa1 = fmaf(k0.y, q0.y, kqa1);
                    kqa1 = fmaf(k0.z, q0.z, kqa1); kqa1 = fmaf(k0.w, q0.w, kqa1);
                    kqa1 = fmaf(k1.x, q1.x, kqa1); kqa1 = fmaf(k1.y, q1.y, kqa1);
                    kqa1 = fmaf(k1.z, q1.z, kqa1); kqa1 = fmaf(k1.w, q1.w, kqa1);
                    kqa1 = fmaf(k2.x, q2v.x, kqa1); kqa1 = fmaf(k2.y, q2v.y, kqa1);
                    kqa1 = fmaf(k2.z, q2v.z, kqa1); kqa1 = fmaf(k2.w, q2v.w, kqa1);
                    kqa1 = fmaf(k3.x, q3.x, kqa1); kqa1 = fmaf(k3.y, q3.y, kqa1);
                    kqa1 = fmaf(k3.z, q3.z, kqa1); kqa1 = fmaf(k3.w, q3.w, kqa1);
                }
                if (cnk == 1 && wu == 15) {            // s = 64 (srel 32)
                    const float* kr = &kcsh[32 * 132 + ib];
                    float4 k0 = *(const float4*)&kr[0], k1 = *(const float4*)&kr[4];
                    float4 k2 = *(const float4*)&kr[8], k3 = *(const float4*)&kr[12];
                    kqa2 = fmaf(k0.x, q0.x, kqa2); kqa2 = fmaf(k0.y, q0.y, kqa2);
                    kqa2 = fmaf(k0.z, q0.z, kqa2); kqa2 = fmaf(k0.w, q0.w, kqa2);
                    kqa2 = fmaf(k1.x, q1.x, kqa2); kqa2 = fmaf(k1.y, q1.y, kqa2);
                    kqa2 = fmaf(k1.z, q1.z, kqa2); kqa2 = fmaf(k1.w, q1.w, kqa2);
                    kqa2 = fmaf(k2.x, q2v.x, kqa2); kqa2 = fmaf(k2.y, q2v.y, kqa2);
                    kqa2 = fmaf(k2.z, q2v.z, kqa2); kqa2 = fmaf(k2.w, q2v.w, kqa2);
                    kqa2 = fmaf(k3.x, q3.x, kqa2); kqa2 = fmaf(k3.y, q3.y, kqa2);
                    kqa2 = fmaf(k3.z, q3.z, kqa2); kqa2 = fmaf(k3.w, q3.w, kqa2);
                }
                __syncthreads();
            }

            // softmax (same butterfly DAG), rows s = base+2wu+rr (+ s=64)
            #pragma unroll
            for (int rr = 0; rr < 3; ++rr) {
                if (rr < 2 || (cnk == 1 && wu == 15)) {
                    int srel = (rr == 2) ? 32 : 2 * wu + rr;
                    int s = base + srel;
                    float lg = (rr == 0) ? kqa0 : ((rr == 1) ? kqa1 : kqa2);
                    float l64v = (lane == 0) ? kq64sh[s] : -3.0e38f;
                    float mm = fmaxf(lg, l64v);
                    #pragma unroll
                    for (int off = 32; off >= 1; off >>= 1) mm = fmaxf(mm, __shfl_xor(mm, off));
                    float e   = expf(lg - mm);
                    float e64 = (lane == 0) ? expf(l64v - mm) : 0.f;
                    float zs = e + e64;
                    #pragma unroll
                    for (int off = 32; off >= 1; off >>= 1) zs += __shfl_xor(zs, off);
                    float inv = 1.0f / zs;
                    smc[srel * 68 + lane] = e * inv;
                    if (lane == 0) smc[srel * 68 + 64] = e64 * inv;
                }
            }
            __syncthreads();

            // att chunk: att[srel][i] = sum_t sm*v (t-ascending); overwrite kcsh
            {
                const int iA = tid & 127;
                const int sg = tid >> 7;
                const bool has5 = (cnk == 1 && sg == 0);
                float aa[5];
                #pragma unroll
                for (int m = 0; m < 5; ++m) aa[m] = 0.f;
                for (int k = 0; k < 16; ++k) {
                    float4 vq = *(const float4*)&vsh[iA * 68 + 4 * k];
                    #pragma unroll
                    for (int m = 0; m < 5; ++m) {
                        if (m < 4 || has5) {
                            int srel = (m < 4) ? (sg + 8 * m) : 32;
                            float4 sq = *(const float4*)&smc[srel * 68 + 4 * k];
                            aa[m] = fmaf(sq.x, vq.x, aa[m]);
                            aa[m] = fmaf(sq.y, vq.y, aa[m]);
                            aa[m] = fmaf(sq.z, vq.z, aa[m]);
                            aa[m] = fmaf(sq.w, vq.w, aa[m]);
                        }
                    }
                }
                float v64 = vsh[iA * 68 + 64];
                #pragma unroll
                for (int m = 0; m < 5; ++m) {
                    if (m < 4 || has5) {
                        int srel = (m < 4) ? (sg + 8 * m) : 32;
                        aa[m] = fmaf(smc[srel * 68 + 64], v64, aa[m]);
                        kcsh[srel * 128 + iA] = aa[m];
                    }
                }
            }
            __syncthreads();

            // pre1 chunk: exact i-ascending chains into acc1[cnk] (+acc1[2])
            {
                const float* l1a = l1 + a * (128 * 128);
                const float* attc = kcsh;
                for (int i0b = 0; i0b < 128; i0b += 4) {
                    float4 av = *(const float4*)&attc[sb * 128 + i0b];
                    float4 av2 = make_float4(0.f, 0.f, 0.f, 0.f);
                    if (cnk == 1 && sb == 0) av2 = *(const float4*)&attc[32 * 128 + i0b];
                    float a0[4] = { av.x, av.y, av.z, av.w };
                    float a2[4] = { av2.x, av2.y, av2.z, av2.w };
                    #pragma unroll
                    for (int r = 0; r < 4; ++r) {
                        float4 lv = *(const float4*)&l1a[(i0b + r) * 128 + h4];
                        if (cnk == 0) {
                            acc1[0].x = fmaf(a0[r], lv.x, acc1[0].x);
                            acc1[0].y = fmaf(a0[r], lv.y, acc1[0].y);
                            acc1[0].z = fmaf(a0[r], lv.z, acc1[0].z);
                            acc1[0].w = fmaf(a0[r], lv.w, acc1[0].w);
                        } else {
                            acc1[1].x = fmaf(a0[r], lv.x, acc1[1].x);
                            acc1[1].y = fmaf(a0[r], lv.y, acc1[1].y);
                            acc1[1].z = fmaf(a0[r], lv.z, acc1[1].z);
                            acc1[1].w = fmaf(a0[r], lv.w, acc1[1].w);
                            if (sb == 0) {
                                acc1[2].x = fmaf(a2[r], lv.x, acc1[2].x);
                                acc1[2].y = fmaf(a2[r], lv.y, acc1[2].y);
                                acc1[2].z = fmaf(a2[r], lv.z, acc1[2].z);
                                acc1[2].w = fmaf(a2[r], lv.w, acc1[2].w);
                            }
                        }
                    }
                }
            }
            __syncthreads();
        }
    }

    // ---- y2T[s][h] = tanh(pre1[s][h])  (YQ swizzle, into vsh region) ----
    float* y2sh = vsh;
    #pragma unroll
    for (int si = 0; si < 3; ++si) {
        if (si < 2 || sb == 0) {
            int s = (si == 2) ? 64 : sb + 32 * si;
            float4 tq;
            tq.x = tanhf(si == 0 ? acc1[0].x : si == 1 ? acc1[1].x : acc1[2].x);
            tq.y = tanhf(si == 0 ? acc1[0].y : si == 1 ? acc1[1].y : acc1[2].y);
            tq.z = tanhf(si == 0 ? acc1[0].z : si == 1 ? acc1[1].z : acc1[2].z);
            tq.w = tanhf(si == 0 ? acc1[0].w : si == 1 ? acc1[1].w : acc1[2].w);
            *(float4*)&y2sh[YQ(s, h4 >> 2)] = tq;
        }
    }
    __syncthreads();

    // =================== stage 2 ===================
    float pre2 = 0.f;   // valid tid < 128
    float* scratch = smc;   // psum / l3p

    for (int a2 = 0; a2 < 2; ++a2) {
        const float* wk2 = a2 ? wk22 : wk21;
        const float* wq2 = a2 ? wq22 : wq21;
        const float* wv2 = a2 ? wv22 : wv21;

        // ---- projections: aQ,aV in regs; col64 side-chain ----
        float aQ[8], aV[8];
        #pragma unroll
        for (int r = 0; r < 8; ++r) { aQ[r] = aV[r] = 0.f; }
        float acc64 = 0.f;          // lane<8: q2col64, 8..15: v2col64, 16..23: k2col
        {
            const int ch = lane >> 3;
            const float* Wc = (ch == 0) ? wq2 : ((ch == 1) ? wv2 : wk2);
            const float* wcrow = Wc + (i0 + (lane & 7)) * 128;

            for (int jb = 0; jb < 16; ++jb) {
                float4 yq0 = *(const float4*)&y2sh[YQ(lane, 2 * jb)];
                float4 yq1 = *(const float4*)&y2sh[YQ(lane, 2 * jb + 1)];
                float4 zq0 = *(const float4*)&y2sh[YQ(64, 2 * jb)];
                float4 zq1 = *(const float4*)&y2sh[YQ(64, 2 * jb + 1)];
                float yv[8]   = { yq0.x, yq0.y, yq0.z, yq0.w, yq1.x, yq1.y, yq1.z, yq1.w };
                float y64v[8] = { zq0.x, zq0.y, zq0.z, zq0.w, zq1.x, zq1.y, zq1.z, zq1.w };
                #pragma unroll
                for (int r = 0; r < 8; ++r) {
                    const float* wqr = wq2 + (i0 + r) * 128 + jb * 8;
                    const float* wvr = wv2 + (i0 + r) * 128 + jb * 8;
                    #pragma unroll
                    for (int u = 0; u < 8; ++u) {
                        aQ[r] = fmaf(wqr[u], yv[u], aQ[r]);
                        aV[r] = fmaf(wvr[u], yv[u], aV[r]);
                    }
                }
                if (lane < 24) {
                    float4 c0 = *(const float4*)&wcrow[jb * 8];
                    float4 c1 = *(const float4*)&wcrow[jb * 8 + 4];
                    acc64 = fmaf(c0.x, y64v[0], acc64);
                    acc64 = fmaf(c0.y, y64v[1], acc64);
                    acc64 = fmaf(c0.z, y64v[2], acc64);
                    acc64 = fmaf(c0.w, y64v[3], acc64);
                    acc64 = fmaf(c1.x, y64v[4], acc64);
                    acc64 = fmaf(c1.y, y64v[5], acc64);
                    acc64 = fmaf(c1.z, y64v[6], acc64);
                    acc64 = fmaf(c1.w, y64v[7], acc64);
                }
            }
            if (lane < 8)                 q64sh[i0 + lane] = acc64;          // q2 col64
            if (lane >= 16 && lane < 24)  k2col[i0 + (lane & 7)] = acc64;    // k2 col64
        }
        __syncthreads();

        // ---- kq2[64][t] via qbuf rotation (i-ascending, exact) ----
        if (wu < 2) {
            *(float4*)&qbufsh[lane * QS + wu * 8]     = make_float4(aQ[0], aQ[1], aQ[2], aQ[3]);
            *(float4*)&qbufsh[lane * QS + wu * 8 + 4] = make_float4(aQ[4], aQ[5], aQ[6], aQ[7]);
        }
        __syncthreads();
        float kqacc = 0.f;
        for (int c = 0; c < 8; ++c) {
            if (c < 7 && (wu >> 1) == c + 1) {
                int sel = (c + 1) & 1, off = (wu & 1) * 8;
                *(float4*)&qbufsh[sel * QBUF + lane * QS + off]     = make_float4(aQ[0], aQ[1], aQ[2], aQ[3]);
                *(float4*)&qbufsh[sel * QBUF + lane * QS + off + 4] = make_float4(aQ[4], aQ[5], aQ[6], aQ[7]);
            }
            if (tid < 65) {
                const float* qr = (tid < 64) ? &qbufsh[(c & 1) * QBUF + tid * QS]
                                             : &q64sh[16 * c];
                float4 q0 = *(const float4*)&qr[0];
                float4 q1 = *(const float4*)&qr[4];
                float4 q2v = *(const float4*)&qr[8];
                float4 q3 = *(const float4*)&qr[12];
                const float* kr = &k2col[16 * c];
                float4 k0 = *(const float4*)&kr[0], k1 = *(const float4*)&kr[4];
                float4 k2 = *(const float4*)&kr[8], k3 = *(const float4*)&kr[12];
                kqacc = fmaf(k0.x, q0.x, kqacc); kqacc = fmaf(k0.y, q0.y, kqacc);
                kqacc = fmaf(k0.z, q0.z, kqacc); kqacc = fmaf(k0.w, q0.w, kqacc);
                kqacc = fmaf(k1.x, q1.x, kqacc); kqacc = fmaf(k1.y, q1.y, kqacc);
                kqacc = fmaf(k1.z, q1.z, kqacc); kqacc = fmaf(k1.w, q1.w, kqacc);
                kqacc = fmaf(k2.x, q2v.x, kqacc); kqacc = fmaf(k2.y, q2v.y, kqacc);
                kqacc = fmaf(k2.z, q2v.z, kqacc); kqacc = fmaf(k2.w, q2v.w, kqacc);
                kqacc = fmaf(k3.x, q3.x, kqacc); kqacc = fmaf(k3.y, q3.y, kqacc);
                kqacc = fmaf(k3.z, q3.z, kqacc);  kqacc = fmaf(k3.w, q3.w, kqacc);
            }
            __syncthreads();
        }
        if (tid < 65) lshf[tid] = kqacc;
        __syncthreads();

        // ---- softmax (same butterfly DAG) ----
        if (tid < 64) {
            float lg   = lshf[lane];
            float l64v = (lane == 0) ? lshf[64] : -3.0e38f;
            float mm = fmaxf(lg, l64v);
            #pragma unroll
            for (int off = 32; off >= 1; off >>= 1) mm = fmaxf(mm, __shfl_xor(mm, off));
            float e   = expf(lg - mm);
            float e64 = (lane == 0) ? expf(l64v - mm) : 0.f;
            float zs = e + e64;
            #pragma unroll
            for (int off = 32; off >= 1; off >>= 1) zs += __shfl_xor(zs, off);
            float inv = 1.0f / zs;
            smr[lane] = e * inv;
            if (lane == 0) smr[64] = e64 * inv;
        }
        __syncthreads();

        // ---- att2 via wave butterfly (post-final-softmax, reassoc-safe) ----
        {
            float part[8];
            float sv = smr[lane];
            #pragma unroll
            for (int r = 0; r < 8; ++r) part[r] = sv * aV[r];
            #pragma unroll
            for (int off = 32; off >= 1; off >>= 1) {
                #pragma unroll
                for (int r = 0; r < 8; ++r) part[r] += __shfl_xor(part[r], off);
            }
            if (lane >= 8 && lane < 16) {
                int r = lane - 8;
                attr[i0 + r] = part[r] + smr[64] * acc64;   // acc64 = v2[i0+r][64]
            }
        }
        __syncthreads();

        // ---- pre2 split-K (post-softmax) ----
        {
            const int hh = tid & 127, cc = tid >> 7;
            const float* l2a = l2 + a2 * (128 * 128);
            float p = 0.f;
            #pragma unroll
            for (int g = 0; g < 4; ++g) {
                int i = cc * 16 + 4 * g;
                float4 av = *(const float4*)&attr[i];
                p = fmaf(av.x, l2a[(i + 0) * 128 + hh], p);
                p = fmaf(av.y, l2a[(i + 1) * 128 + hh], p);
                p = fmaf(av.z, l2a[(i + 2) * 128 + hh], p);
                p = fmaf(av.w, l2a[(i + 3) * 128 + hh], p);
            }
            scratch[cc * 128 + hh] = p;
        }
        __syncthreads();
        if (tid < 128) {
            float red = scratch[tid];
            #pragma unroll
            for (int c = 1; c < 8; ++c) red += scratch[c * 128 + tid];
            pre2 += red;
        }
        __syncthreads();
    }

    if (tid < 128) y4sh[tid] = tanhf(pre2);
    __syncthreads();

    // t3[o] = sum_h y4[h]*L3[h][o]  (split-K, post-softmax)
    {
        const int oo = tid & 63, cc = tid >> 6;   // cc 0..15
        float p = 0.f;
        #pragma unroll
        for (int u = 0; u < 8; ++u) {
            int h = cc * 8 + u;
            p = fmaf(y4sh[h], L3[h * 64 + oo], p);
        }
        scratch[cc * 64 + oo] = p;
    }
    __syncthreads();
    if (tid < 64) {
        float t3 = scratch[tid];
        #pragma unroll
        for (int c = 1; c < 16; ++c) t3 += scratch[c * 64 + tid];
        float y5 = tanhf(t3);
        float sc = y5 * L4[tid];
        #pragma unroll
        for (int off = 32; off >= 1; off >>= 1) sc += __shfl_xor(sc, off);
        if (tid == 0) out[b] = sc;
    }
}

extern "C" void kernel_launch(void* const* d_in, const int* in_sizes, int n_in,
                              void* d_out, int out_size, void* d_ws, size_t ws_size,
                              hipStream_t stream) {
    const float* in0  = (const float*)d_in[0];
    const float* emb  = (const float*)d_in[1];
    const float* wk11 = (const float*)d_in[2];
    const float* wq11 = (const float*)d_in[3];
    const float* wv11 = (const float*)d_in[4];
    const float* wk12 = (const float*)d_in[5];
    const float* wq12 = (const float*)d_in[6];
    const float* wv12 = (const float*)d_in[7];
    const float* l1   = (const float*)d_in[8];
    const float* wk21 = (const float*)d_in[9];
    const float* wq21 = (const float*)d_in[10];
    const float* wv21 = (const float*)d_in[11];
    const float* wk22 = (const float*)d_in[12];
    const float* wq22 = (const float*)d_in[13];
    const float* wv22 = (const float*)d_in[14];
    const float* l2   = (const float*)d_in[15];
    const float* l3   = (const float*)d_in[16];
    const float* l4   = (const float*)d_in[17];
    float* out = (float*)d_out;

    int B = in_sizes[0] / 64;   // 8192

    literal_kernel<<<B, 1024, 0, stream>>>(in0, emb,
                                           wk11, wq11, wv11, wk12, wq12, wv12, l1,
                                           wk21, wq21, wv21, wk22, wq22, wv22, l2,
                                           l3, l4, out);
}

// Round 9
// 5879.583 us; speedup vs baseline: 1.6069x; 1.6069x over previous
//
#include <hip/hip_runtime.h>
#include <math.h>

// Round 9: two INDEPENDENT 512-thread blocks per CU (r8 failed because a 2nd
// 16-wave block needs 8 waves/SIMD > SGPR cap 7, and its c-loop spilled).
// 512 threads = 8 waves; 2 blocks = 4 waves/SIMD (fits), gated only by
// LDS <= 80 KB. This kernel uses ~70.3 KB:
//  - projections in two 64-row i-passes; k/q chunks transit LDS (17-18 KB),
//    kq accumulates i-ascending across passes in registers (exact r5 chain)
//  - softmax rows stay in registers; att fused into the owner wave via
//    __shfl broadcast of sm[t], strict t-ascending (bit-identical chain)
//  - v full (stride 65, conflict-free); att overlays dead k/q region;
//    y2 overlays v; stage-2 v2 in regs, att2 butterfly (post-final-softmax)
// All chains feeding any softmax are fmaf-sequence-identical to r5/r7.

#define YQ(s, q) ((s) * 128 + 4 * ((q) ^ ((s) & 7)))
#define KA_STR 68
#define QA_STR 72
#define QA_BASE 4420   // floats; byte offset 17680 (16B aligned)

__global__
__attribute__((amdgpu_flat_work_group_size(512, 512)))
__attribute__((amdgpu_waves_per_eu(4, 8)))
void literal_kernel(const float* __restrict__ in0,
                    const float* __restrict__ emb,
                    const float* __restrict__ wk11, const float* __restrict__ wq11,
                    const float* __restrict__ wv11,
                    const float* __restrict__ wk12, const float* __restrict__ wq12,
                    const float* __restrict__ wv12,
                    const float* __restrict__ l1,
                    const float* __restrict__ wk21, const float* __restrict__ wq21,
                    const float* __restrict__ wv21,
                    const float* __restrict__ wk22, const float* __restrict__ wq22,
                    const float* __restrict__ wv22,
                    const float* __restrict__ l2,
                    const float* __restrict__ L3, const float* __restrict__ L4,
                    float* __restrict__ out)
{
    __shared__ __align__(16) float vsh[8320];   // v[i][t] stride 65; later y2 (YQ)
    __shared__ __align__(16) float R1[9028];    // kA[65][68] @0, qA[64][72] @4420;
                                                // att[s*128+i] overlay; scratch
    __shared__ __align__(16) float k64sh[128];  // k[:,64] (st1) / k2[:,64] (st2)
    __shared__ __align__(16) float q64sh[128];  // q[:,64] / q2[:,64]
    __shared__ float kq64sh[68];
    __shared__ __align__(16) float smr[68];
    __shared__ __align__(16) float attr[128];
    __shared__ float y4sh[128];

    const int tid  = threadIdx.x;
    const int lane = tid & 63;
    const int wu   = __builtin_amdgcn_readfirstlane(tid >> 6);   // wave 0..7
    const long b   = blockIdx.x;
    const float xr = in0[b * 64 + lane];

    float* kA = R1;
    float* qA = R1 + QA_BASE;

    const int h4 = (tid & 31) * 4;
    const int sb = tid >> 5;          // 0..15
    float4 acc1[5];
    #pragma unroll
    for (int si = 0; si < 5; ++si) acc1[si] = make_float4(0.f, 0.f, 0.f, 0.f);

    // =================== stage 1 ===================
    for (int a = 0; a < 2; ++a) {
        const float* wk = a ? wk12 : wk11;
        const float* wq = a ? wq12 : wq11;
        const float* wv = a ? wv12 : wv11;

        float kqa[8];
        #pragma unroll
        for (int m = 0; m < 8; ++m) kqa[m] = 0.f;
        float kq64acc = 0.f, kqr64acc = 0.f, corner = 0.f;   // wave-0 extras

        for (int p = 0; p < 2; ++p) {
            const int ip0 = p * 64 + wu * 8;
            // ---- projection pass p: rows ip0..ip0+7, lanes = column s/t ----
            float aK[8], aQ[8], aV[8];
            #pragma unroll
            for (int r = 0; r < 8; ++r) { aK[r] = aQ[r] = aV[r] = 0.f; }
            float acc64 = 0.f;                     // lane<8:K64 8..15:Q64 16..23:V64
            {
                const int ch = lane >> 3;
                const float* Wc = (ch == 0) ? wk : ((ch == 1) ? wq : wv);
                const float* wcrow = Wc + (ip0 + (lane & 7)) * 128;
                for (int jq = 0; jq < 32; ++jq) {
                    const float* erow = emb + (jq * 4) * 65;
                    float yv[4], y64v[4];
                    #pragma unroll
                    for (int u = 0; u < 4; ++u) {
                        yv[u]   = erow[u * 65 + lane] * xr;   // bit-exact y
                        y64v[u] = erow[u * 65 + 64];
                    }
                    #pragma unroll
                    for (int r = 0; r < 8; ++r) {
                        const float* wkr = wk + (ip0 + r) * 128 + jq * 4;
                        const float* wqr = wq + (ip0 + r) * 128 + jq * 4;
                        const float* wvr = wv + (ip0 + r) * 128 + jq * 4;
                        #pragma unroll
                        for (int u = 0; u < 4; ++u) {
                            aK[r] = fmaf(wkr[u], yv[u], aK[r]);
                            aQ[r] = fmaf(wqr[u], yv[u], aQ[r]);
                            aV[r] = fmaf(wvr[u], yv[u], aV[r]);
                        }
                    }
                    if (lane < 24) {
                        float4 c0 = *(const float4*)&wcrow[jq * 4];
                        acc64 = fmaf(c0.x, y64v[0], acc64);
                        acc64 = fmaf(c0.y, y64v[1], acc64);
                        acc64 = fmaf(c0.z, y64v[2], acc64);
                        acc64 = fmaf(c0.w, y64v[3], acc64);
                    }
                }
                *(float4*)&kA[lane * KA_STR + wu * 8]     = make_float4(aK[0], aK[1], aK[2], aK[3]);
                *(float4*)&kA[lane * KA_STR + wu * 8 + 4] = make_float4(aK[4], aK[5], aK[6], aK[7]);
                *(float4*)&qA[lane * QA_STR + wu * 8]     = make_float4(aQ[0], aQ[1], aQ[2], aQ[3]);
                *(float4*)&qA[lane * QA_STR + wu * 8 + 4] = make_float4(aQ[4], aQ[5], aQ[6], aQ[7]);
                #pragma unroll
                for (int r = 0; r < 8; ++r) vsh[(ip0 + r) * 65 + lane] = aV[r];
                if (lane < 8)            k64sh[ip0 + lane] = acc64;
                else if (lane < 16)      q64sh[ip0 + (lane & 7)] = acc64;
                else if (lane < 24)      vsh[(ip0 + (lane & 7)) * 65 + 64] = acc64;
            }
            __syncthreads();

            // ---- kq partial over chunk p (global i = p*64 + 4*iq + u) ----
            for (int iq = 0; iq < 16; ++iq) {
                float4 qq = *(const float4*)&qA[lane * QA_STR + iq * 4];
                #pragma unroll
                for (int m = 0; m < 8; ++m) {
                    float4 kk = *(const float4*)&kA[(wu + 8 * m) * KA_STR + iq * 4];
                    kqa[m] = fmaf(kk.x, qq.x, kqa[m]);
                    kqa[m] = fmaf(kk.y, qq.y, kqa[m]);
                    kqa[m] = fmaf(kk.z, qq.z, kqa[m]);
                    kqa[m] = fmaf(kk.w, qq.w, kqa[m]);
                }
                if (wu == 0) {
                    float4 kc = *(const float4*)&k64sh[p * 64 + iq * 4];
                    float4 qc = *(const float4*)&q64sh[p * 64 + iq * 4];
                    kqr64acc = fmaf(kc.x, qq.x, kqr64acc);   // kq[64][t=lane]
                    kqr64acc = fmaf(kc.y, qq.y, kqr64acc);
                    kqr64acc = fmaf(kc.z, qq.z, kqr64acc);
                    kqr64acc = fmaf(kc.w, qq.w, kqr64acc);
                    float4 ks = *(const float4*)&kA[lane * KA_STR + iq * 4];
                    kq64acc = fmaf(ks.x, qc.x, kq64acc);     // kq[s=lane][64]
                    kq64acc = fmaf(ks.y, qc.y, kq64acc);
                    kq64acc = fmaf(ks.z, qc.z, kq64acc);
                    kq64acc = fmaf(ks.w, qc.w, kq64acc);
                    if (lane == 0) {
                        corner = fmaf(kc.x, qc.x, corner);   // kq[64][64]
                        corner = fmaf(kc.y, qc.y, corner);
                        corner = fmaf(kc.z, qc.z, corner);
                        corner = fmaf(kc.w, qc.w, corner);
                    }
                }
            }
            if (p == 1 && wu == 0) {
                kq64sh[lane] = kq64acc;
                if (lane == 0) kq64sh[64] = corner;
            }
            __syncthreads();
        }

        // ---- softmax in registers (same butterfly DAG) + fused att ----
        float smv[9], sm64v[9];
        #pragma unroll
        for (int m = 0; m < 9; ++m) { smv[m] = 0.f; sm64v[m] = 0.f; }
        #pragma unroll
        for (int m = 0; m < 9; ++m) {
            if (m < 8 || wu == 0) {
                int s = (m == 8) ? 64 : (wu + 8 * m);
                float lg   = (m == 8) ? kqr64acc : kqa[m];
                float l64v = (lane == 0) ? kq64sh[s] : -3.0e38f;
                float mm = fmaxf(lg, l64v);
                #pragma unroll
                for (int off = 32; off >= 1; off >>= 1) mm = fmaxf(mm, __shfl_xor(mm, off));
                float e   = expf(lg - mm);
                float e64 = (lane == 0) ? expf(l64v - mm) : 0.f;
                float zs = e + e64;
                #pragma unroll
                for (int off = 32; off >= 1; off >>= 1) zs += __shfl_xor(zs, off);
                float inv = 1.0f / zs;
                smv[m] = e * inv;
                sm64v[m] = e64 * inv;
            }
        }
        // att[s][i] = sum_t sm[s][t]*v[i][t], strict t-ascending (exact chain)
        {
            float aa0[9], aa1[9];
            #pragma unroll
            for (int m = 0; m < 9; ++m) { aa0[m] = 0.f; aa1[m] = 0.f; }
            const float* vr0 = &vsh[lane * 65];
            const float* vr1 = &vsh[(lane + 64) * 65];
            for (int t = 0; t < 64; ++t) {
                float v0 = vr0[t], v1 = vr1[t];
                #pragma unroll
                for (int m = 0; m < 9; ++m) {
                    if (m < 8 || wu == 0) {
                        float smt = __shfl(smv[m], t);
                        aa0[m] = fmaf(smt, v0, aa0[m]);
                        aa1[m] = fmaf(smt, v1, aa1[m]);
                    }
                }
            }
            float v0e = vr0[64], v1e = vr1[64];
            #pragma unroll
            for (int m = 0; m < 9; ++m) {
                if (m < 8 || wu == 0) {
                    float smt = __shfl(sm64v[m], 0);
                    aa0[m] = fmaf(smt, v0e, aa0[m]);
                    aa1[m] = fmaf(smt, v1e, aa1[m]);
                    int s = (m == 8) ? 64 : (wu + 8 * m);
                    R1[s * 128 + lane]      = aa0[m];
                    R1[s * 128 + lane + 64] = aa1[m];
                }
            }
        }
        __syncthreads();

        // ---- pre1[s][h] += sum_i att[s][i]*l1a[i][h]  (exact i-ascending) ----
        {
            const float* l1a = l1 + a * 16384;
            for (int i0b = 0; i0b < 128; i0b += 4) {
                float4 av0 = *(const float4*)&R1[(sb +  0) * 128 + i0b];
                float4 av1 = *(const float4*)&R1[(sb + 16) * 128 + i0b];
                float4 av2 = *(const float4*)&R1[(sb + 32) * 128 + i0b];
                float4 av3 = *(const float4*)&R1[(sb + 48) * 128 + i0b];
                float4 av4 = make_float4(0.f, 0.f, 0.f, 0.f);
                if (sb == 0) av4 = *(const float4*)&R1[64 * 128 + i0b];
                float a0[4] = { av0.x, av0.y, av0.z, av0.w };
                float a1[4] = { av1.x, av1.y, av1.z, av1.w };
                float a2[4] = { av2.x, av2.y, av2.z, av2.w };
                float a3[4] = { av3.x, av3.y, av3.z, av3.w };
                float a4[4] = { av4.x, av4.y, av4.z, av4.w };
                #pragma unroll
                for (int r = 0; r < 4; ++r) {
                    float4 lv = *(const float4*)&l1a[(i0b + r) * 128 + h4];
                    acc1[0].x = fmaf(a0[r], lv.x, acc1[0].x);
                    acc1[0].y = fmaf(a0[r], lv.y, acc1[0].y);
                    acc1[0].z = fmaf(a0[r], lv.z, acc1[0].z);
                    acc1[0].w = fmaf(a0[r], lv.w, acc1[0].w);
                    acc1[1].x = fmaf(a1[r], lv.x, acc1[1].x);
                    acc1[1].y = fmaf(a1[r], lv.y, acc1[1].y);
                    acc1[1].z = fmaf(a1[r], lv.z, acc1[1].z);
                    acc1[1].w = fmaf(a1[r], lv.w, acc1[1].w);
                    acc1[2].x = fmaf(a2[r], lv.x, acc1[2].x);
                    acc1[2].y = fmaf(a2[r], lv.y, acc1[2].y);
                    acc1[2].z = fmaf(a2[r], lv.z, acc1[2].z);
                    acc1[2].w = fmaf(a2[r], lv.w, acc1[2].w);
                    acc1[3].x = fmaf(a3[r], lv.x, acc1[3].x);
                    acc1[3].y = fmaf(a3[r], lv.y, acc1[3].y);
                    acc1[3].z = fmaf(a3[r], lv.z, acc1[3].z);
                    acc1[3].w = fmaf(a3[r], lv.w, acc1[3].w);
                    if (sb == 0) {
                        acc1[4].x = fmaf(a4[r], lv.x, acc1[4].x);
                        acc1[4].y = fmaf(a4[r], lv.y, acc1[4].y);
                        acc1[4].z = fmaf(a4[r], lv.z, acc1[4].z);
                        acc1[4].w = fmaf(a4[r], lv.w, acc1[4].w);
                    }
                }
            }
        }
        __syncthreads();
    }

    // ---- y2[t][h] = tanh(pre1), YQ-swizzled into vsh (v dead) ----
    #pragma unroll
    for (int si = 0; si < 5; ++si) {
        if (si < 4 || sb == 0) {
            int s = (si == 4) ? 64 : (sb + 16 * si);
            float4 tq;
            tq.x = tanhf(acc1[si].x);
            tq.y = tanhf(acc1[si].y);
            tq.z = tanhf(acc1[si].z);
            tq.w = tanhf(acc1[si].w);
            *(float4*)&vsh[YQ(s, h4 >> 2)] = tq;
        }
    }
    __syncthreads();

    // =================== stage 2 ===================
    float pre2 = 0.f;   // valid tid < 128
    for (int a2 = 0; a2 < 2; ++a2) {
        const float* wk2 = a2 ? wk22 : wk21;
        const float* wq2 = a2 ? wq22 : wq21;
        const float* wv2 = a2 ? wv22 : wv21;

        float v2A[8], v2B[8];
        float v2c64A = 0.f, v2c64B = 0.f;
        float kq2acc = 0.f, corner2 = 0.f;

        for (int p = 0; p < 2; ++p) {
            const int ip0 = p * 64 + wu * 8;
            float aQ[8], aV[8];
            #pragma unroll
            for (int r = 0; r < 8; ++r) { aQ[r] = aV[r] = 0.f; }
            float acc64 = 0.f;       // lane<8: q2col64  8..15: v2col64  16..23: k2col64
            {
                const int ch = lane >> 3;
                const float* Wc = (ch == 0) ? wq2 : ((ch == 1) ? wv2 : wk2);
                const float* wcrow = Wc + (ip0 + (lane & 7)) * 128;
                for (int jq = 0; jq < 32; ++jq) {
                    float4 yq = *(const float4*)&vsh[YQ(lane, jq)];
                    float4 zq = *(const float4*)&vsh[YQ(64, jq)];
                    float yv[4]   = { yq.x, yq.y, yq.z, yq.w };
                    float y64v[4] = { zq.x, zq.y, zq.z, zq.w };
                    #pragma unroll
                    for (int r = 0; r < 8; ++r) {
                        const float* wqr = wq2 + (ip0 + r) * 128 + jq * 4;
                        const float* wvr = wv2 + (ip0 + r) * 128 + jq * 4;
                        #pragma unroll
                        for (int u = 0; u < 4; ++u) {
                            aQ[r] = fmaf(wqr[u], yv[u], aQ[r]);
                            aV[r] = fmaf(wvr[u], yv[u], aV[r]);
                        }
                    }
                    if (lane < 24) {
                        float4 c0 = *(const float4*)&wcrow[jq * 4];
                        acc64 = fmaf(c0.x, y64v[0], acc64);
                        acc64 = fmaf(c0.y, y64v[1], acc64);
                        acc64 = fmaf(c0.z, y64v[2], acc64);
                        acc64 = fmaf(c0.w, y64v[3], acc64);
                    }
                }
                *(float4*)&qA[lane * QA_STR + wu * 8]     = make_float4(aQ[0], aQ[1], aQ[2], aQ[3]);
                *(float4*)&qA[lane * QA_STR + wu * 8 + 4] = make_float4(aQ[4], aQ[5], aQ[6], aQ[7]);
                if (lane < 8)            q64sh[ip0 + lane] = acc64;
                else if (lane < 16)      { if (p == 0) v2c64A = acc64; else v2c64B = acc64; }
                else if (lane < 24)      k64sh[ip0 + (lane & 7)] = acc64;
                #pragma unroll
                for (int r = 0; r < 8; ++r) {
                    if (p == 0) v2A[r] = aV[r]; else v2B[r] = aV[r];
                }
            }
            __syncthreads();

            // kq2[64][t] partial (exact i-ascending), wave 0 only
            if (wu == 0) {
                for (int iq = 0; iq < 16; ++iq) {
                    float4 qq = *(const float4*)&qA[lane * QA_STR + iq * 4];
                    float4 kk = *(const float4*)&k64sh[p * 64 + iq * 4];
                    kq2acc = fmaf(kk.x, qq.x, kq2acc);
                    kq2acc = fmaf(kk.y, qq.y, kq2acc);
                    kq2acc = fmaf(kk.z, qq.z, kq2acc);
                    kq2acc = fmaf(kk.w, qq.w, kq2acc);
                    if (lane == 0) {
                        float4 qz = *(const float4*)&q64sh[p * 64 + iq * 4];
                        corner2 = fmaf(kk.x, qz.x, corner2);
                        corner2 = fmaf(kk.y, qz.y, corner2);
                        corner2 = fmaf(kk.z, qz.z, corner2);
                        corner2 = fmaf(kk.w, qz.w, corner2);
                    }
                }
            }
            __syncthreads();
        }

        // softmax2 on wave 0 (same butterfly DAG), publish to smr
        if (wu == 0) {
            float lg   = kq2acc;
            float l64v = (lane == 0) ? corner2 : -3.0e38f;
            float mm = fmaxf(lg, l64v);
            #pragma unroll
            for (int off = 32; off >= 1; off >>= 1) mm = fmaxf(mm, __shfl_xor(mm, off));
            float e   = expf(lg - mm);
            float e64 = (lane == 0) ? expf(l64v - mm) : 0.f;
            float zs = e + e64;
            #pragma unroll
            for (int off = 32; off >= 1; off >>= 1) zs += __shfl_xor(zs, off);
            float inv = 1.0f / zs;
            smr[lane] = e * inv;
            if (lane == 0) smr[64] = e64 * inv;
        }
        __syncthreads();

        // att2 via butterfly (post-final-softmax, reassociation-safe)
        {
            float sv = smr[lane];
            float part[16];
            #pragma unroll
            for (int r = 0; r < 8; ++r) { part[r] = sv * v2A[r]; part[8 + r] = sv * v2B[r]; }
            #pragma unroll
            for (int off = 32; off >= 1; off >>= 1) {
                #pragma unroll
                for (int r = 0; r < 16; ++r) part[r] += __shfl_xor(part[r], off);
            }
            float sm64 = smr[64];
            int rr = lane & 15;
            float c64A = __shfl(v2c64A, 8 + (lane & 7));
            float c64B = __shfl(v2c64B, 8 + (lane & 7));
            float myval = 0.f;
            #pragma unroll
            for (int r = 0; r < 16; ++r) myval = (rr == r) ? part[r] : myval;
            if (lane < 16) {
                int irow = (rr < 8) ? (wu * 8 + rr) : (64 + wu * 8 + (rr - 8));
                float c64 = (rr < 8) ? c64A : c64B;
                attr[irow] = myval + sm64 * c64;
            }
        }
        __syncthreads();

        // pre2 split-K (post-softmax)
        {
            const int hh = tid & 127, cc = tid >> 7;   // cc 0..3
            const float* l2a = l2 + a2 * 16384;
            float pp = 0.f;
            #pragma unroll
            for (int g = 0; g < 8; ++g) {
                int i = cc * 32 + 4 * g;
                float4 av = *(const float4*)&attr[i];
                pp = fmaf(av.x, l2a[(i + 0) * 128 + hh], pp);
                pp = fmaf(av.y, l2a[(i + 1) * 128 + hh], pp);
                pp = fmaf(av.z, l2a[(i + 2) * 128 + hh], pp);
                pp = fmaf(av.w, l2a[(i + 3) * 128 + hh], pp);
            }
            R1[cc * 128 + hh] = pp;
        }
        __syncthreads();
        if (tid < 128) {
            float red = R1[tid];
            #pragma unroll
            for (int c = 1; c < 4; ++c) red += R1[c * 128 + tid];
            pre2 += red;
        }
        __syncthreads();
    }

    if (tid < 128) y4sh[tid] = tanhf(pre2);
    __syncthreads();

    // t3[o] = sum_h y4[h]*L3[h][o]  (split-K, post-softmax)
    {
        const int oo = tid & 63, cc = tid >> 6;   // cc 0..7
        float pp = 0.f;
        #pragma unroll
        for (int u = 0; u < 16; ++u) {
            int h = cc * 16 + u;
            pp = fmaf(y4sh[h], L3[h * 64 + oo], pp);
        }
        R1[cc * 64 + oo] = pp;
    }
    __syncthreads();
    if (tid < 64) {
        float t3 = R1[tid];
        #pragma unroll
        for (int c = 1; c < 8; ++c) t3 += R1[c * 64 + tid];
        float y5 = tanhf(t3);
        float sc = y5 * L4[tid];
        #pragma unroll
        for (int off = 32; off >= 1; off >>= 1) sc += __shfl_xor(sc, off);
        if (tid == 0) out[b] = sc;
    }
}

extern "C" void kernel_launch(void* const* d_in, const int* in_sizes, int n_in,
                              void* d_out, int out_size, void* d_ws, size_t ws_size,
                              hipStream_t stream) {
    const float* in0  = (const float*)d_in[0];
    const float* emb  = (const float*)d_in[1];
    const float* wk11 = (const float*)d_in[2];
    const float* wq11 = (const float*)d_in[3];
    const float* wv11 = (const float*)d_in[4];
    const float* wk12 = (const float*)d_in[5];
    const float* wq12 = (const float*)d_in[6];
    const float* wv12 = (const float*)d_in[7];
    const float* l1   = (const float*)d_in[8];
    const float* wk21 = (const float*)d_in[9];
    const float* wq21 = (const float*)d_in[10];
    const float* wv21 = (const float*)d_in[11];
    const float* wk22 = (const float*)d_in[12];
    const float* wq22 = (const float*)d_in[13];
    const float* wv22 = (const float*)d_in[14];
    const float* l2   = (const float*)d_in[15];
    const float* l3   = (const float*)d_in[16];
    const float* l4   = (const float*)d_in[17];
    float* out = (float*)d_out;

    int B = in_sizes[0] / 64;   // 8192

    literal_kernel<<<B, 512, 0, stream>>>(in0, emb,
                                          wk11, wq11, wv11, wk12, wq12, wv12, l1,
                                          wk21, wq21, wv21, wk22, wq22, wv22, l2,
                                          l3, l4, out);
}